// Round 1
// baseline (8238.242 us; speedup 1.0000x reference)
//
#include <hip/hip_runtime.h>
#include <hip/hip_bf16.h>

// Fire_model_hybrid: IMV-LSTM scan (T=64) + temporal attention + head.
// v1 strategy: bf16 MFMA gate GEMMs with direct-from-global fragments (no LDS),
// online attention accumulation, f32 cell state. Correctness-first.

#define B_SZ 512
#define T_SZ 64
#define IN_DIMX 21
#define D_F 19
#define N_U 128
#define G_SZ 2432        // D_F * N_U
#define KPAD 2464        // padded gate-GEMM K: [h(2432) | x(19) | zero(13)]
#define KXOFF 2432
#define NPAIR 9728       // B_SZ * D_F

typedef __attribute__((ext_vector_type(8))) short bf16x8;
typedef __attribute__((ext_vector_type(4))) float f32x4;

__device__ __forceinline__ float sigmoidf_(float v) { return 1.0f / (1.0f + expf(-v)); }
__device__ __forceinline__ int fmap(int j) { return j < 16 ? j : j + 2; }  // 16->18,17->19,18->20

// ---------------- preprocess: weight repack (f32->bf16), transposes, zero-init ----------------
__global__ __launch_bounds__(256) void prep_kernel(
    const float* __restrict__ x,
    const float* __restrict__ Wi, const float* __restrict__ Wf, const float* __restrict__ Wo,
    const float* __restrict__ Wj,
    __hip_bfloat16* __restrict__ Wt,    // [3][G_SZ][KPAD]
    __hip_bfloat16* __restrict__ Wjt,   // [D_F][128][128]  (k_out major, i minor)
    __hip_bfloat16* __restrict__ xpad,  // [T][B][32]
    __hip_bfloat16* __restrict__ hbuf0, // [B][G_SZ]
    float* __restrict__ apre)           // [2][NPAIR]
{
    int i = blockIdx.x * 256 + threadIdx.x;
    const int NWT = 3 * G_SZ * KPAD;
    if (i < NWT) {
        int gate = i / (G_SZ * KPAD);
        int rem  = i - gate * (G_SZ * KPAD);
        int g = rem / KPAD, q = rem - g * KPAD;
        const float* W = gate == 0 ? Wi : (gate == 1 ? Wf : Wo);
        float v = 0.0f;
        if (q < KXOFF)      v = W[g * 2451 + 19 + q];       // h-part: orig cols 19..2450
        else if (q < 2451)  v = W[g * 2451 + (q - KXOFF)];  // x-part: orig cols 0..18
        Wt[i] = __float2bfloat16(v);
        return;
    }
    i -= NWT;
    if (i < D_F * 128 * 128) {
        int d = i / 16384, rem = i - d * 16384;
        int ko = rem >> 7, ii = rem & 127;
        Wjt[d * 16384 + ko * 128 + ii] = __float2bfloat16(Wj[d * 16384 + ii * 128 + ko]);
        return;
    }
    i -= D_F * 128 * 128;
    if (i < T_SZ * B_SZ * 32) {
        int t = i / (B_SZ * 32), rem = i - t * (B_SZ * 32);
        int b = rem >> 5, j = rem & 31;
        float v = 0.0f;
        if (j < D_F) v = x[(b * T_SZ + t) * IN_DIMX + fmap(j)];
        xpad[i] = __float2bfloat16(v);
        return;
    }
    i -= T_SZ * B_SZ * 32;
    if (i < 2 * NPAIR) { apre[i] = 0.0f; return; }
    i -= 2 * NPAIR;
    if (i < B_SZ * G_SZ) hbuf0[i] = __float2bfloat16(0.0f);
}

// ---------------- per-timestep kernel ----------------
// grid = 304 blocks (8 m-blocks x 38 n-blocks), 256 threads (4 waves).
// Tile: 64 batch rows x 64 gate cols x {i,f,o} + j-candidate. Wave w owns n-frag column w.
__global__ __launch_bounds__(256) void step_kernel(
    int t,
    const __hip_bfloat16* __restrict__ Wt,
    const __hip_bfloat16* __restrict__ Wjt,
    const __hip_bfloat16* __restrict__ xpad,
    const __hip_bfloat16* __restrict__ hcur,
    __hip_bfloat16* __restrict__ hnext,
    float* __restrict__ cbuf,
    float* __restrict__ apre,   // [2][NPAIR]
    float* __restrict__ asum,   // [NPAIR]
    float* __restrict__ gacc,   // [B][G_SZ]
    const float* __restrict__ x,
    const float* __restrict__ Uj, const float* __restrict__ bj,
    const float* __restrict__ Wib, const float* __restrict__ Wfb, const float* __restrict__ Wob,
    const float* __restrict__ Fa, const float* __restrict__ Fab)
{
    // ---- prologue: finish attention for step t-1 (alpha sums complete at launch boundary) ----
    if (t > 0) {
        int tp1 = (t - 1) & 1;
        int half = threadIdx.x >> 7;
        int k = threadIdx.x & 127;
        for (int it = 0; it < 16; ++it) {
            int pair = blockIdx.x * 32 + it * 2 + half;   // 304*32 == NPAIR exactly
            int d = pair % 19;
            float a = expf(tanhf(apre[tp1 * NPAIR + pair] + Fab[d]));
            int b = pair / 19;
            int idx = b * G_SZ + d * 128 + k;
            float hv = __bfloat162float(hcur[idx]);
            if (t == 1) gacc[idx] = a * hv; else gacc[idx] += a * hv;
            if (k == 0) {
                if (t == 1) asum[pair] = a; else asum[pair] += a;
                apre[tp1 * NPAIR + pair] = 0.0f;   // ready for reuse at step t+1
            }
        }
    }

    const int mb = blockIdx.x / 38, nb = blockIdx.x % 38;
    const int b0 = mb * 64, g0 = nb * 64;
    const int lane = threadIdx.x & 63, wv = threadIdx.x >> 6;
    const int r = lane & 15, hi = lane >> 4, kq = hi * 8;

    f32x4 ai[4], af4[4], ao[4], aj[4];
#pragma unroll
    for (int m = 0; m < 4; ++m) { ai[m] = (f32x4)0.0f; af4[m] = (f32x4)0.0f; ao[m] = (f32x4)0.0f; aj[m] = (f32x4)0.0f; }

    const __hip_bfloat16* aA = hcur + (size_t)(b0 + r) * G_SZ + kq;
    const __hip_bfloat16* aX = xpad + ((size_t)t * B_SZ + (b0 + r)) * 32 + kq;
    const __hip_bfloat16* bI = Wt + (size_t)(g0 + wv * 16 + r) * KPAD + kq;
    const __hip_bfloat16* bF = bI + (size_t)G_SZ * KPAD;
    const __hip_bfloat16* bO = bF + (size_t)G_SZ * KPAD;

    // ---- gate GEMM: K = 2464 (76 iters from h, 1 iter from xpad) ----
    for (int kk = 0; kk < 77; ++kk) {
        const int ko = kk * 32;
        bf16x8 vb0 = *(const bf16x8*)(bI + ko);
        bf16x8 vb1 = *(const bf16x8*)(bF + ko);
        bf16x8 vb2 = *(const bf16x8*)(bO + ko);
        bf16x8 va[4];
        if (kk < 76) {
#pragma unroll
            for (int mi = 0; mi < 4; ++mi) va[mi] = *(const bf16x8*)(aA + ko + mi * 16 * G_SZ);
        } else {
#pragma unroll
            for (int mi = 0; mi < 4; ++mi) va[mi] = *(const bf16x8*)(aX + (ko - KXOFF) + mi * 16 * 32);
        }
#pragma unroll
        for (int mi = 0; mi < 4; ++mi) {
            ai[mi]  = __builtin_amdgcn_mfma_f32_16x16x32_bf16(va[mi], vb0, ai[mi], 0, 0, 0);
            af4[mi] = __builtin_amdgcn_mfma_f32_16x16x32_bf16(va[mi], vb1, af4[mi], 0, 0, 0);
            ao[mi]  = __builtin_amdgcn_mfma_f32_16x16x32_bf16(va[mi], vb2, ao[mi], 0, 0, 0);
        }
    }

    // ---- j candidate GEMM: K = 128 over this block's variable d ----
    const int d = g0 >> 7;
    const int gk0 = g0 & 127;
    const __hip_bfloat16* aJ = hcur + (size_t)(b0 + r) * G_SZ + d * 128 + kq;
    const __hip_bfloat16* bJ = Wjt + ((size_t)d * 128 + gk0 + wv * 16 + r) * 128 + kq;
#pragma unroll
    for (int kk = 0; kk < 4; ++kk) {
        bf16x8 vb = *(const bf16x8*)(bJ + kk * 32);
#pragma unroll
        for (int mi = 0; mi < 4; ++mi) {
            bf16x8 va = *(const bf16x8*)(aJ + kk * 32 + mi * 16 * G_SZ);
            aj[mi] = __builtin_amdgcn_mfma_f32_16x16x32_bf16(va, vb, aj[mi], 0, 0, 0);
        }
    }

    // ---- epilogue: gates, cell update, h write, alpha partial dot ----
    const int g = g0 + wv * 16 + (lane & 15);
    const int kw = g & 127;
    const float wib = Wib[g], wfb = Wfb[g], wob = Wob[g];
    const float uj = Uj[d * 128 + kw], bjv = bj[d * 128 + kw], fav = Fa[d * 128 + kw];
    const int xcol = fmap(d);

#pragma unroll
    for (int mi = 0; mi < 4; ++mi) {
        float psum[4];
#pragma unroll
        for (int rr = 0; rr < 4; ++rr) {
            const int b = b0 + mi * 16 + hi * 4 + rr;
            float iv = sigmoidf_(ai[mi][rr] + wib);
            float fv = sigmoidf_(af4[mi][rr] + wfb);
            float ov = sigmoidf_(ao[mi][rr] + wob);
            float xv = x[(b * T_SZ + t) * IN_DIMX + xcol];
            float jv = tanhf(aj[mi][rr] + xv * uj + bjv);
            float cold = (t > 0) ? cbuf[(size_t)b * G_SZ + g] : 0.0f;
            float cv = cold * fv + iv * jv;
            cbuf[(size_t)b * G_SZ + g] = cv;
            float hv = ov * tanhf(cv);
            hnext[(size_t)b * G_SZ + g] = __float2bfloat16(hv);
            psum[rr] = hv * fav;
        }
#pragma unroll
        for (int m = 1; m < 16; m <<= 1) {
#pragma unroll
            for (int rr = 0; rr < 4; ++rr) psum[rr] += __shfl_xor(psum[rr], m, 64);
        }
        if ((lane & 15) == 0) {
#pragma unroll
            for (int rr = 0; rr < 4; ++rr) {
                int b = b0 + mi * 16 + hi * 4 + rr;
                atomicAdd(&apre[(t & 1) * NPAIR + b * 19 + d], psum[rr]);
            }
        }
    }
}

// ---------------- final: finish t=63 attention, betas/Phi head, limitation gates ----------------
__global__ __launch_bounds__(256) void final_kernel(
    const float* __restrict__ x,
    const __hip_bfloat16* __restrict__ h63,   // hbuf[0]
    const float* __restrict__ apre, float* __restrict__ asum, float* __restrict__ gacc,
    const float* __restrict__ Fab,
    const float* __restrict__ Fbw, const float* __restrict__ Fbb,
    const float* __restrict__ Pw,  const float* __restrict__ Pb,
    const float* __restrict__ faw, const float* __restrict__ fab,
    const float* __restrict__ hsw, const float* __restrict__ hsb,
    float* __restrict__ out)
{
    const int b = blockIdx.x, tid = threadIdx.x;
    // finish attention accumulation for t=63 (apre buffer 1)
    for (int e = tid; e < G_SZ; e += 256) {
        int d = e >> 7;
        float a = expf(tanhf(apre[NPAIR + b * 19 + d] + Fab[d]));
        int idx = b * G_SZ + e;
        gacc[idx] += a * __bfloat162float(h63[idx]);
    }
    if (tid < 19) asum[b * 19 + tid] += expf(tanhf(apre[NPAIR + b * 19 + tid] + Fab[tid]));
    __syncthreads();

    const int wv = tid >> 6, lane = tid & 63;
    __shared__ float snum[4], sden[4];
    float num = 0.0f, den = 0.0f;
    for (int d = wv; d < 19; d += 4) {
        float asv = asum[b * 19 + d];
        float mua = 0.0f, bea = 0.0f;
#pragma unroll
        for (int j2 = 0; j2 < 4; ++j2) {
            int e = lane + j2 * 64;  // 0..255 over hg = [g_n(128) | h_fin(128)]
            float hg = (e < 128) ? (gacc[b * G_SZ + d * 128 + e] / asv)
                                 : __bfloat162float(h63[b * G_SZ + d * 128 + (e - 128)]);
            mua += hg * Pw[e];
            bea += hg * Fbw[e];
        }
        for (int m = 1; m < 64; m <<= 1) { mua += __shfl_xor(mua, m, 64); bea += __shfl_xor(bea, m, 64); }
        if (lane == 0) {
            float mu = mua + Pb[0];
            float be = expf(tanhf(bea + Fbb[0]));
            num += be * mu; den += be;
        }
    }
    if (lane == 0) { snum[wv] = num; sden[wv] = den; }
    __syncthreads();
    if (tid == 0) {
        float n = 0.0f, dd = 0.0f;
        for (int w = 0; w < 4; ++w) { n += snum[w]; dd += sden[w]; }
        float fFF = sigmoidf_(n / dd);
        float xn = x[(b * T_SZ + 63) * IN_DIMX + 0];
        float xp = x[(b * T_SZ + 63) * IN_DIMX + 16];
        float fn = sigmoidf_(xn * faw[0] + fab[0]);
        float fp = sigmoidf_(xp * hsw[0] + hsb[0]);
        out[b] = fFF * fn * fp;
    }
}

extern "C" void kernel_launch(void* const* d_in, const int* in_sizes, int n_in,
                              void* d_out, int out_size, void* d_ws, size_t ws_size,
                              hipStream_t stream) {
    const float* x   = (const float*)d_in[0];
    const float* Uj  = (const float*)d_in[1];
    const float* Wj  = (const float*)d_in[2];
    const float* bj  = (const float*)d_in[3];
    const float* Wi  = (const float*)d_in[4];
    const float* Wib = (const float*)d_in[5];
    const float* Wf  = (const float*)d_in[6];
    const float* Wfb = (const float*)d_in[7];
    const float* Wo  = (const float*)d_in[8];
    const float* Wob = (const float*)d_in[9];
    const float* Fa  = (const float*)d_in[10];
    const float* Fab = (const float*)d_in[11];
    const float* Fbw = (const float*)d_in[12];
    const float* Fbb = (const float*)d_in[13];
    const float* Pw  = (const float*)d_in[14];
    const float* Pb  = (const float*)d_in[15];
    const float* faw = (const float*)d_in[16];
    const float* fab = (const float*)d_in[17];
    const float* hsw = (const float*)d_in[18];
    const float* hsb = (const float*)d_in[19];

    char* ws = (char*)d_ws;
    size_t off = 0;
    auto alloc = [&](size_t bytes) { void* p = ws + off; off += (bytes + 255) & ~(size_t)255; return p; };

    __hip_bfloat16* Wt    = (__hip_bfloat16*)alloc((size_t)3 * G_SZ * KPAD * 2);
    __hip_bfloat16* Wjt   = (__hip_bfloat16*)alloc((size_t)D_F * 128 * 128 * 2);
    __hip_bfloat16* xpad  = (__hip_bfloat16*)alloc((size_t)T_SZ * B_SZ * 32 * 2);
    __hip_bfloat16* hbuf  = (__hip_bfloat16*)alloc((size_t)2 * B_SZ * G_SZ * 2);
    float* cbuf  = (float*)alloc((size_t)B_SZ * G_SZ * 4);
    float* apre  = (float*)alloc((size_t)2 * NPAIR * 4);
    float* asumb = (float*)alloc((size_t)NPAIR * 4);
    float* gacc  = (float*)alloc((size_t)B_SZ * G_SZ * 4);

    const int PREP_TOTAL = 3 * G_SZ * KPAD + D_F * 128 * 128 + T_SZ * B_SZ * 32 + 2 * NPAIR + B_SZ * G_SZ;
    prep_kernel<<<(PREP_TOTAL + 255) / 256, 256, 0, stream>>>(x, Wi, Wf, Wo, Wj, Wt, Wjt, xpad, hbuf, apre);

    const size_t HB = (size_t)B_SZ * G_SZ;
    for (int t = 0; t < T_SZ; ++t) {
        step_kernel<<<304, 256, 0, stream>>>(t, Wt, Wjt, xpad,
            hbuf + (t & 1) * HB, hbuf + ((t + 1) & 1) * HB,
            cbuf, apre, asumb, gacc,
            x, Uj, bj, Wib, Wfb, Wob, Fa, Fab);
    }
    final_kernel<<<B_SZ, 256, 0, stream>>>(x, hbuf /* buf0 = h(63) */, apre, asumb, gacc,
        Fab, Fbw, Fbb, Pw, Pb, faw, fab, hsw, hsb, (float*)d_out);
}

// Round 2
// 5626.439 us; speedup vs baseline: 1.4642x; 1.4642x over previous
//
#include <hip/hip_runtime.h>
#include <hip/hip_bf16.h>

// Fire_model_hybrid: IMV-LSTM scan (T=64) + temporal attention + head.
// v2: 8-wave blocks, global_load_lds staging into frag-ready LDS slots,
// depth-3 pipeline with counted vmcnt (one barrier per k-step), XCD swizzle.

#define B_SZ 512
#define T_SZ 64
#define IN_DIMX 21
#define D_F 19
#define G_SZ 2432        // D_F * 128
#define KPAD 2464        // [h(2432) | x(19) | zero(13)]
#define KXOFF 2432
#define NPAIR 9728       // B_SZ * D_F

typedef __attribute__((ext_vector_type(8))) short bf16x8;
typedef __attribute__((ext_vector_type(4))) float f32x4;

__device__ __forceinline__ float sigmoidf_(float v) { return 1.0f / (1.0f + expf(-v)); }
__device__ __forceinline__ int fmap(int j) { return j < 16 ? j : j + 2; }

// ---------------- preprocess (unchanged from v1) ----------------
__global__ __launch_bounds__(256) void prep_kernel(
    const float* __restrict__ x,
    const float* __restrict__ Wi, const float* __restrict__ Wf, const float* __restrict__ Wo,
    const float* __restrict__ Wj,
    __hip_bfloat16* __restrict__ Wt,    // [3][G_SZ][KPAD]
    __hip_bfloat16* __restrict__ Wjt,   // [D_F][128][128]
    __hip_bfloat16* __restrict__ xpad,  // [T][B][32]
    __hip_bfloat16* __restrict__ hbuf0,
    float* __restrict__ apre)
{
    int i = blockIdx.x * 256 + threadIdx.x;
    const int NWT = 3 * G_SZ * KPAD;
    if (i < NWT) {
        int gate = i / (G_SZ * KPAD);
        int rem  = i - gate * (G_SZ * KPAD);
        int g = rem / KPAD, q = rem - g * KPAD;
        const float* W = gate == 0 ? Wi : (gate == 1 ? Wf : Wo);
        float v = 0.0f;
        if (q < KXOFF)      v = W[g * 2451 + 19 + q];
        else if (q < 2451)  v = W[g * 2451 + (q - KXOFF)];
        Wt[i] = __float2bfloat16(v);
        return;
    }
    i -= NWT;
    if (i < D_F * 128 * 128) {
        int d = i / 16384, rem = i - d * 16384;
        int ko = rem >> 7, ii = rem & 127;
        Wjt[d * 16384 + ko * 128 + ii] = __float2bfloat16(Wj[d * 16384 + ii * 128 + ko]);
        return;
    }
    i -= D_F * 128 * 128;
    if (i < T_SZ * B_SZ * 32) {
        int t = i / (B_SZ * 32), rem = i - t * (B_SZ * 32);
        int b = rem >> 5, j = rem & 31;
        float v = 0.0f;
        if (j < D_F) v = x[(b * T_SZ + t) * IN_DIMX + fmap(j)];
        xpad[i] = __float2bfloat16(v);
        return;
    }
    i -= T_SZ * B_SZ * 32;
    if (i < 2 * NPAIR) { apre[i] = 0.0f; return; }
    i -= 2 * NPAIR;
    if (i < B_SZ * G_SZ) hbuf0[i] = __float2bfloat16(0.0f);
}

// ---------------- per-timestep kernel (v2) ----------------
// grid = 304 (XCD-swizzled: mb = bid&7, nb = bid>>3), 512 threads (8 waves).
// Block tile: 64 rows x 64 gate-cols x {i,f,o} + j. Wave w: mh=w>>2 (32 rows), nq=w&3 (16 cols).
// LDS: 4 k-step buffers x 16 frag-slots x 1KB. Slot L<4: A-frag mi=L; L>=4: B gate=(L-4)>>2, nq=(L-4)&3.
__global__ __launch_bounds__(512) void step_kernel(
    int t,
    const __hip_bfloat16* __restrict__ Wt,
    const __hip_bfloat16* __restrict__ Wjt,
    const __hip_bfloat16* __restrict__ xpad,
    const __hip_bfloat16* __restrict__ hcur,
    __hip_bfloat16* __restrict__ hnext,
    float* __restrict__ cbuf,
    float* __restrict__ apre,   // [2][NPAIR]
    float* __restrict__ asum,   // [NPAIR]
    float* __restrict__ gacc,   // [B][G_SZ]
    const float* __restrict__ x,
    const float* __restrict__ Uj, const float* __restrict__ bj,
    const float* __restrict__ Wib, const float* __restrict__ Wfb, const float* __restrict__ Wob,
    const float* __restrict__ Fa, const float* __restrict__ Fab)
{
    __shared__ __align__(16) __hip_bfloat16 sbuf[4 * 16 * 512];   // 64 KB
    const int tid = threadIdx.x;

    // ---- prologue: finish attention for step t-1 ----
    if (t > 0) {
        int tp1 = (t - 1) & 1;
        int quarter = tid >> 7;          // 0..3
        int k = tid & 127;
        for (int it = 0; it < 8; ++it) {
            int pair = blockIdx.x * 32 + it * 4 + quarter;   // 304*32 == NPAIR
            int d = pair % 19;
            float a = expf(tanhf(apre[tp1 * NPAIR + pair] + Fab[d]));
            int b = pair / 19;
            int idx = b * G_SZ + d * 128 + k;
            float hv = __bfloat162float(hcur[idx]);
            if (t == 1) gacc[idx] = a * hv; else gacc[idx] += a * hv;
            if (k == 0) {
                if (t == 1) asum[pair] = a; else asum[pair] += a;
                apre[tp1 * NPAIR + pair] = 0.0f;
            }
        }
    }

    const int mb = blockIdx.x & 7, nb = blockIdx.x >> 3;   // XCD swizzle: same-nb blocks share an XCD
    const int b0 = mb * 64, g0 = nb * 64;
    const int w = tid >> 6, lane = tid & 63;
    const int mh = w >> 2, nq = w & 3;
    const int rl = lane & 15, ch = lane >> 4;
    const int L0 = 2 * w;
    const bool isA = (w < 2);

    // staging source pointers for this wave's two slots
    const __hip_bfloat16 *s0m, *s1m, *s0x = nullptr, *s1x = nullptr;
    if (isA) {
        s0m = hcur + (size_t)(b0 + L0 * 16 + rl) * G_SZ + ch * 8;
        s1m = hcur + (size_t)(b0 + (L0 + 1) * 16 + rl) * G_SZ + ch * 8;
        s0x = xpad + ((size_t)t * B_SZ + b0 + L0 * 16 + rl) * 32 + ch * 8;
        s1x = xpad + ((size_t)t * B_SZ + b0 + (L0 + 1) * 16 + rl) * 32 + ch * 8;
    } else {
        const int gt0 = (L0 - 4) >> 2, nqa = (L0 - 4) & 3;
        const int gt1 = (L0 - 3) >> 2, nqb = (L0 - 3) & 3;
        s0m = Wt + ((size_t)gt0 * G_SZ + g0 + nqa * 16 + rl) * KPAD + ch * 8;
        s1m = Wt + ((size_t)gt1 * G_SZ + g0 + nqb * 16 + rl) * KPAD + ch * 8;
    }

    auto STAGE = [&](int kk) {
        __hip_bfloat16* dst = sbuf + (kk & 3) * 8192 + L0 * 512;   // wave-uniform base
        const __hip_bfloat16 *p0, *p1;
        if (isA && kk == 76) { p0 = s0x; p1 = s1x; }
        else { p0 = s0m + kk * 32; p1 = s1m + kk * 32; }
        __builtin_amdgcn_global_load_lds((const __attribute__((address_space(1))) void*)p0,
                                         (__attribute__((address_space(3))) void*)dst, 16, 0, 0);
        __builtin_amdgcn_global_load_lds((const __attribute__((address_space(1))) void*)p1,
                                         (__attribute__((address_space(3))) void*)(dst + 512), 16, 0, 0);
    };

    f32x4 acc[3][2], aj[2];
#pragma unroll
    for (int g2 = 0; g2 < 3; ++g2) { acc[g2][0] = (f32x4)0.0f; acc[g2][1] = (f32x4)0.0f; }
    aj[0] = (f32x4)0.0f; aj[1] = (f32x4)0.0f;

    STAGE(0); STAGE(1); STAGE(2);

    for (int kk = 0; kk < 77; ++kk) {
        // counted vmcnt: leave the 2 most recent stages (4 loads) in flight
        if (kk <= 74)      asm volatile("s_waitcnt vmcnt(4)" ::: "memory");
        else if (kk == 75) asm volatile("s_waitcnt vmcnt(2)" ::: "memory");
        else               asm volatile("s_waitcnt vmcnt(0)" ::: "memory");
        __builtin_amdgcn_s_barrier();
        asm volatile("" ::: "memory");
        __builtin_amdgcn_sched_barrier(0);
        if (kk <= 73) STAGE(kk + 3);   // writes buf[(kk-1)&3], fully consumed at iter kk-1

        const __hip_bfloat16* bp = sbuf + (kk & 3) * 8192;
        bf16x8 va0 = *(const bf16x8*)(bp + (mh * 2 + 0) * 512 + lane * 8);
        bf16x8 va1 = *(const bf16x8*)(bp + (mh * 2 + 1) * 512 + lane * 8);
        bf16x8 vb0 = *(const bf16x8*)(bp + (4 + nq) * 512 + lane * 8);
        bf16x8 vb1 = *(const bf16x8*)(bp + (8 + nq) * 512 + lane * 8);
        bf16x8 vb2 = *(const bf16x8*)(bp + (12 + nq) * 512 + lane * 8);
        acc[0][0] = __builtin_amdgcn_mfma_f32_16x16x32_bf16(va0, vb0, acc[0][0], 0, 0, 0);
        acc[0][1] = __builtin_amdgcn_mfma_f32_16x16x32_bf16(va1, vb0, acc[0][1], 0, 0, 0);
        acc[1][0] = __builtin_amdgcn_mfma_f32_16x16x32_bf16(va0, vb1, acc[1][0], 0, 0, 0);
        acc[1][1] = __builtin_amdgcn_mfma_f32_16x16x32_bf16(va1, vb1, acc[1][1], 0, 0, 0);
        acc[2][0] = __builtin_amdgcn_mfma_f32_16x16x32_bf16(va0, vb2, acc[2][0], 0, 0, 0);
        acc[2][1] = __builtin_amdgcn_mfma_f32_16x16x32_bf16(va1, vb2, acc[2][1], 0, 0, 0);
    }

    // ---- j candidate GEMM: K=128, direct from global (L2-resident) ----
    const int d = g0 >> 7;
    const int gk0 = g0 & 127;
    const __hip_bfloat16* aJ = hcur + (size_t)(b0 + mh * 32 + rl) * G_SZ + d * 128 + ch * 8;
    const __hip_bfloat16* bJ = Wjt + ((size_t)d * 128 + gk0 + nq * 16 + rl) * 128 + ch * 8;
#pragma unroll
    for (int kk = 0; kk < 4; ++kk) {
        bf16x8 vb = *(const bf16x8*)(bJ + kk * 32);
#pragma unroll
        for (int mi = 0; mi < 2; ++mi) {
            bf16x8 va = *(const bf16x8*)(aJ + kk * 32 + (size_t)mi * 16 * G_SZ);
            aj[mi] = __builtin_amdgcn_mfma_f32_16x16x32_bf16(va, vb, aj[mi], 0, 0, 0);
        }
    }

    // ---- epilogue: gates, cell update, h write, alpha partial dot ----
    const int g = g0 + nq * 16 + rl;
    const int kw = g & 127;
    const float wib = Wib[g], wfb = Wfb[g], wob = Wob[g];
    const float uj = Uj[d * 128 + kw], bjv = bj[d * 128 + kw], fav = Fa[d * 128 + kw];
    const int xcol = fmap(d);

#pragma unroll
    for (int mi = 0; mi < 2; ++mi) {
        float psum[4];
#pragma unroll
        for (int rr = 0; rr < 4; ++rr) {
            const int b = b0 + mh * 32 + mi * 16 + ch * 4 + rr;
            float iv = sigmoidf_(acc[0][mi][rr] + wib);
            float fv = sigmoidf_(acc[1][mi][rr] + wfb);
            float ov = sigmoidf_(acc[2][mi][rr] + wob);
            float xv = x[(b * T_SZ + t) * IN_DIMX + xcol];
            float jv = tanhf(aj[mi][rr] + xv * uj + bjv);
            float cold = (t > 0) ? cbuf[(size_t)b * G_SZ + g] : 0.0f;
            float cv = cold * fv + iv * jv;
            cbuf[(size_t)b * G_SZ + g] = cv;
            float hv = ov * tanhf(cv);
            hnext[(size_t)b * G_SZ + g] = __float2bfloat16(hv);
            psum[rr] = hv * fav;
        }
#pragma unroll
        for (int m2 = 1; m2 < 16; m2 <<= 1) {
#pragma unroll
            for (int rr = 0; rr < 4; ++rr) psum[rr] += __shfl_xor(psum[rr], m2, 64);
        }
        if (rl == 0) {
#pragma unroll
            for (int rr = 0; rr < 4; ++rr) {
                int b = b0 + mh * 32 + mi * 16 + ch * 4 + rr;
                atomicAdd(&apre[(t & 1) * NPAIR + b * 19 + d], psum[rr]);
            }
        }
    }
}

// ---------------- final (unchanged from v1) ----------------
__global__ __launch_bounds__(256) void final_kernel(
    const float* __restrict__ x,
    const __hip_bfloat16* __restrict__ h63,
    const float* __restrict__ apre, float* __restrict__ asum, float* __restrict__ gacc,
    const float* __restrict__ Fab,
    const float* __restrict__ Fbw, const float* __restrict__ Fbb,
    const float* __restrict__ Pw,  const float* __restrict__ Pb,
    const float* __restrict__ faw, const float* __restrict__ fab,
    const float* __restrict__ hsw, const float* __restrict__ hsb,
    float* __restrict__ out)
{
    const int b = blockIdx.x, tid = threadIdx.x;
    for (int e = tid; e < G_SZ; e += 256) {
        int d = e >> 7;
        float a = expf(tanhf(apre[NPAIR + b * 19 + d] + Fab[d]));
        int idx = b * G_SZ + e;
        gacc[idx] += a * __bfloat162float(h63[idx]);
    }
    if (tid < 19) asum[b * 19 + tid] += expf(tanhf(apre[NPAIR + b * 19 + tid] + Fab[tid]));
    __syncthreads();

    const int wv = tid >> 6, lane = tid & 63;
    __shared__ float snum[4], sden[4];
    float num = 0.0f, den = 0.0f;
    for (int d = wv; d < 19; d += 4) {
        float asv = asum[b * 19 + d];
        float mua = 0.0f, bea = 0.0f;
#pragma unroll
        for (int j2 = 0; j2 < 4; ++j2) {
            int e = lane + j2 * 64;
            float hg = (e < 128) ? (gacc[b * G_SZ + d * 128 + e] / asv)
                                 : __bfloat162float(h63[b * G_SZ + d * 128 + (e - 128)]);
            mua += hg * Pw[e];
            bea += hg * Fbw[e];
        }
        for (int m = 1; m < 64; m <<= 1) { mua += __shfl_xor(mua, m, 64); bea += __shfl_xor(bea, m, 64); }
        if (lane == 0) {
            float mu = mua + Pb[0];
            float be = expf(tanhf(bea + Fbb[0]));
            num += be * mu; den += be;
        }
    }
    if (lane == 0) { snum[wv] = num; sden[wv] = den; }
    __syncthreads();
    if (tid == 0) {
        float n = 0.0f, dd = 0.0f;
        for (int w2 = 0; w2 < 4; ++w2) { n += snum[w2]; dd += sden[w2]; }
        float fFF = sigmoidf_(n / dd);
        float xn = x[(b * T_SZ + 63) * IN_DIMX + 0];
        float xp = x[(b * T_SZ + 63) * IN_DIMX + 16];
        float fn = sigmoidf_(xn * faw[0] + fab[0]);
        float fp = sigmoidf_(xp * hsw[0] + hsb[0]);
        out[b] = fFF * fn * fp;
    }
}

extern "C" void kernel_launch(void* const* d_in, const int* in_sizes, int n_in,
                              void* d_out, int out_size, void* d_ws, size_t ws_size,
                              hipStream_t stream) {
    const float* x   = (const float*)d_in[0];
    const float* Uj  = (const float*)d_in[1];
    const float* Wj  = (const float*)d_in[2];
    const float* bj  = (const float*)d_in[3];
    const float* Wi  = (const float*)d_in[4];
    const float* Wib = (const float*)d_in[5];
    const float* Wf  = (const float*)d_in[6];
    const float* Wfb = (const float*)d_in[7];
    const float* Wo  = (const float*)d_in[8];
    const float* Wob = (const float*)d_in[9];
    const float* Fa  = (const float*)d_in[10];
    const float* Fab = (const float*)d_in[11];
    const float* Fbw = (const float*)d_in[12];
    const float* Fbb = (const float*)d_in[13];
    const float* Pw  = (const float*)d_in[14];
    const float* Pb  = (const float*)d_in[15];
    const float* faw = (const float*)d_in[16];
    const float* fab = (const float*)d_in[17];
    const float* hsw = (const float*)d_in[18];
    const float* hsb = (const float*)d_in[19];

    char* ws = (char*)d_ws;
    size_t off = 0;
    auto alloc = [&](size_t bytes) { void* p = ws + off; off += (bytes + 255) & ~(size_t)255; return p; };

    __hip_bfloat16* Wt    = (__hip_bfloat16*)alloc((size_t)3 * G_SZ * KPAD * 2);
    __hip_bfloat16* Wjt   = (__hip_bfloat16*)alloc((size_t)D_F * 128 * 128 * 2);
    __hip_bfloat16* xpad  = (__hip_bfloat16*)alloc((size_t)T_SZ * B_SZ * 32 * 2);
    __hip_bfloat16* hbuf  = (__hip_bfloat16*)alloc((size_t)2 * B_SZ * G_SZ * 2);
    float* cbuf  = (float*)alloc((size_t)B_SZ * G_SZ * 4);
    float* apre  = (float*)alloc((size_t)2 * NPAIR * 4);
    float* asumb = (float*)alloc((size_t)NPAIR * 4);
    float* gacc  = (float*)alloc((size_t)B_SZ * G_SZ * 4);

    const int PREP_TOTAL = 3 * G_SZ * KPAD + D_F * 128 * 128 + T_SZ * B_SZ * 32 + 2 * NPAIR + B_SZ * G_SZ;
    prep_kernel<<<(PREP_TOTAL + 255) / 256, 256, 0, stream>>>(x, Wi, Wf, Wo, Wj, Wt, Wjt, xpad, hbuf, apre);

    const size_t HB = (size_t)B_SZ * G_SZ;
    for (int t = 0; t < T_SZ; ++t) {
        step_kernel<<<304, 512, 0, stream>>>(t, Wt, Wjt, xpad,
            hbuf + (t & 1) * HB, hbuf + ((t + 1) & 1) * HB,
            cbuf, apre, asumb, gacc,
            x, Uj, bj, Wib, Wfb, Wob, Fa, Fab);
    }
    final_kernel<<<B_SZ, 256, 0, stream>>>(x, hbuf, apre, asumb, gacc,
        Fab, Fbw, Fbb, Pw, Pb, faw, fab, hsw, hsb, (float*)d_out);
}

// Round 3
// 5111.476 us; speedup vs baseline: 1.6117x; 1.1007x over previous
//
#include <hip/hip_runtime.h>
#include <hip/hip_bf16.h>

// Fire_model_hybrid: IMV-LSTM scan (T=64) + temporal attention + head.
// v3: barrier-free step kernel. Weights AND h-state stored in MFMA-frag-linear
// layout -> all operands stream global->register via fully coalesced 1KB loads.
// 32x32x16 bf16 MFMA, grid 152 (8 m-blocks x 19 d-panels), 8 waves/block,
// wave = 32 rows x 32 cols x {i,f,o,j}. XCD-grouped block mapping.

#define B_SZ 512
#define T_SZ 64
#define IN_DIMX 21
#define D_F 19
#define G_SZ 2432        // D_F * 128
#define NPAIR 9728       // B_SZ * D_F
#define NK16 154         // 2464/16 : 152 h-frags + 2 x-frags
#define HFRAGS 152

typedef __attribute__((ext_vector_type(8))) short bf16x8;
typedef __attribute__((ext_vector_type(16))) float f32x16;

__device__ __forceinline__ float sigmoidf_(float v) { return 1.0f / (1.0f + expf(-v)); }
__device__ __forceinline__ int fmap(int j) { return j < 16 ? j : j + 2; }

// h frag-layout: [mb 8][mi 2][k16 152][lane 64][e 8]
__device__ __forceinline__ size_t hidx(int b, int gg) {
    int mb2 = b >> 6, r = b & 63, mi = r >> 5, bl = r & 31;
    int k16 = gg >> 4, half = (gg >> 3) & 1, e = gg & 7;
    return ((((size_t)(mb2 * 2 + mi) * HFRAGS + k16) * 64) + bl + 32 * half) * 8 + e;
}

// ---------------- preprocess: frag-linear weight/x packing, zero-init ----------------
__global__ __launch_bounds__(256) void prep_kernel(
    const float* __restrict__ x,
    const float* __restrict__ Wi, const float* __restrict__ Wf, const float* __restrict__ Wo,
    const float* __restrict__ Wj,
    __hip_bfloat16* __restrict__ Wt2,   // [3][19][4][154][512]
    __hip_bfloat16* __restrict__ Wjt2,  // [19][4][8][512]
    __hip_bfloat16* __restrict__ xfr,   // [64][8][2][2][512]
    __hip_bfloat16* __restrict__ hfr0,  // [8][2][152][512]
    float* __restrict__ apre)           // [2][NPAIR]
{
    int i = blockIdx.x * 256 + threadIdx.x;
    const int NWT = 3 * 19 * 4 * NK16 * 512;            // 17,965,056
    if (i < NWT) {
        int e = i & 7, lane = (i >> 3) & 63, fi = i >> 9;
        int k16 = fi % NK16, ff = fi / NK16;
        int s = ff & 3, ff2 = ff >> 2;
        int d = ff2 % 19, gate = ff2 / 19;
        int gcol = d * 128 + s * 32 + (lane & 31);
        int k = k16 * 16 + (lane >> 5) * 8 + e;
        const float* W = gate == 0 ? Wi : (gate == 1 ? Wf : Wo);
        float v = 0.0f;
        if (k < 2432)      v = W[gcol * 2451 + 19 + k];     // h-part: orig cols 19..2450
        else if (k < 2451) v = W[gcol * 2451 + (k - 2432)]; // x-part: orig cols 0..18
        Wt2[i] = __float2bfloat16(v);
        return;
    }
    i -= NWT;
    if (i < 19 * 4 * 8 * 512) {                          // 311,296
        int e = i & 7, lane = (i >> 3) & 63, fi = i >> 9;
        int k16 = fi & 7, ff = fi >> 3;
        int s = ff & 3, d = ff >> 2;
        int col = s * 32 + (lane & 31);
        int kin = k16 * 16 + (lane >> 5) * 8 + e;
        Wjt2[i] = __float2bfloat16(Wj[d * 16384 + kin * 128 + col]);
        return;
    }
    i -= 19 * 4 * 8 * 512;
    if (i < 64 * 8 * 2 * 2 * 512) {                      // 1,048,576
        int e = i & 7, lane = (i >> 3) & 63, fi = i >> 9;
        int k16 = fi & 1, ff = fi >> 1;
        int mi = ff & 1, ff2 = ff >> 1;
        int mb = ff2 & 7, tt = ff2 >> 3;
        int b = mb * 64 + mi * 32 + (lane & 31);
        int kloc = k16 * 16 + (lane >> 5) * 8 + e;
        float v = 0.0f;
        if (kloc < 19) v = x[(b * T_SZ + tt) * IN_DIMX + fmap(kloc)];
        xfr[i] = __float2bfloat16(v);
        return;
    }
    i -= 64 * 8 * 2 * 2 * 512;
    if (i < 8 * 2 * HFRAGS * 512) { hfr0[i] = __float2bfloat16(0.0f); return; }  // 1,245,184
    i -= 8 * 2 * HFRAGS * 512;
    if (i < 2 * NPAIR) apre[i] = 0.0f;
}

#define LOADSET(aa0, aa1, b00, b01, b10, b11, b20, b21, kk) do { \
    int f_ = 2 * (kk); \
    if ((kk) == 76) { aa0 = pAx[0]; aa1 = pAx[64]; } \
    else { aa0 = pA[(size_t)f_ * 64]; aa1 = pA[(size_t)f_ * 64 + 64]; } \
    b00 = pB0[(size_t)f_ * 64]; b01 = pB0[(size_t)f_ * 64 + 64]; \
    b10 = pB1[(size_t)f_ * 64]; b11 = pB1[(size_t)f_ * 64 + 64]; \
    b20 = pB2[(size_t)f_ * 64]; b21 = pB2[(size_t)f_ * 64 + 64]; } while (0)

#define MFMASET(aa0, aa1, b00, b01, b10, b11, b20, b21) do { \
    acc0 = __builtin_amdgcn_mfma_f32_32x32x16_bf16(aa0, b00, acc0, 0, 0, 0); \
    acc1 = __builtin_amdgcn_mfma_f32_32x32x16_bf16(aa0, b10, acc1, 0, 0, 0); \
    acc2 = __builtin_amdgcn_mfma_f32_32x32x16_bf16(aa0, b20, acc2, 0, 0, 0); \
    acc0 = __builtin_amdgcn_mfma_f32_32x32x16_bf16(aa1, b01, acc0, 0, 0, 0); \
    acc1 = __builtin_amdgcn_mfma_f32_32x32x16_bf16(aa1, b11, acc1, 0, 0, 0); \
    acc2 = __builtin_amdgcn_mfma_f32_32x32x16_bf16(aa1, b21, acc2, 0, 0, 0); } while (0)

// ---------------- per-timestep kernel ----------------
// grid = 152 : XCD-grouped bijection g = 19*(bid%8) + bid/8 ; nb = g>>3 (panel), mb = g&7.
__global__ __launch_bounds__(512, 2) void step_kernel(
    int t,
    const __hip_bfloat16* __restrict__ Wt2,
    const __hip_bfloat16* __restrict__ Wjt2,
    const __hip_bfloat16* __restrict__ xfr,
    const __hip_bfloat16* __restrict__ hcur,
    __hip_bfloat16* __restrict__ hnext,
    float* __restrict__ cbuf,
    float* __restrict__ apre,   // [2][NPAIR]
    float* __restrict__ asum,   // [NPAIR]
    float* __restrict__ gacc,   // [B][G_SZ]
    const float* __restrict__ x,
    const float* __restrict__ Uj, const float* __restrict__ bj,
    const float* __restrict__ Wib, const float* __restrict__ Wfb, const float* __restrict__ Wob,
    const float* __restrict__ Fa, const float* __restrict__ Fab)
{
    __shared__ __align__(16) __hip_bfloat16 strans[8][1024];   // 16 KB: per-wave 32x32 transpose
    const int tid = threadIdx.x;
    const int g = 19 * (blockIdx.x & 7) + (blockIdx.x >> 3);
    const int nb = g >> 3, mb = g & 7;                 // nb: d-panel 0..18, mb: row-block 0..7
    const int w = tid >> 6, lane = tid & 63;
    const int mi = w >> 2, s = w & 3;                  // wave = rows [mb*64+mi*32,+32) x cols [nb*128+s*32,+32)

    // ---- main gate GEMM: all operands direct global->register, frag-linear ----
    const bf16x8* pA  = (const bf16x8*)hcur + ((size_t)(mb * 2 + mi) * HFRAGS) * 64 + lane;
    const bf16x8* pAx = (const bf16x8*)xfr + ((size_t)((t * 8 + mb) * 2 + mi) * 2) * 64 + lane;
    const bf16x8* pB0 = (const bf16x8*)Wt2 + ((size_t)(0 * 76 + nb * 4 + s) * NK16) * 64 + lane;
    const bf16x8* pB1 = (const bf16x8*)Wt2 + ((size_t)(1 * 76 + nb * 4 + s) * NK16) * 64 + lane;
    const bf16x8* pB2 = (const bf16x8*)Wt2 + ((size_t)(2 * 76 + nb * 4 + s) * NK16) * 64 + lane;

    f32x16 acc0 = (f32x16)0.0f, acc1 = (f32x16)0.0f, acc2 = (f32x16)0.0f;
    bf16x8 aE0, aE1, bE00, bE01, bE10, bE11, bE20, bE21;
    bf16x8 aO0, aO1, bO00, bO01, bO10, bO11, bO20, bO21;

    LOADSET(aE0, aE1, bE00, bE01, bE10, bE11, bE20, bE21, 0);
    for (int kk2 = 0; kk2 < 39; ++kk2) {
        if (kk2 < 38) LOADSET(aO0, aO1, bO00, bO01, bO10, bO11, bO20, bO21, 2 * kk2 + 1);
        MFMASET(aE0, aE1, bE00, bE01, bE10, bE11, bE20, bE21);
        if (kk2 < 38) {
            LOADSET(aE0, aE1, bE00, bE01, bE10, bE11, bE20, bE21, 2 * kk2 + 2);
            MFMASET(aO0, aO1, bO00, bO01, bO10, bO11, bO20, bO21);
        }
    }

    // ---- attention finish for step t-1 (independent of this step's math) ----
    if (t > 0) {
        int tp1 = (t - 1) & 1;
        int quarter = tid >> 7, k = tid & 127;
        for (int it = 0; it < 16; ++it) {
            int pair = g * 64 + it * 4 + quarter;      // 152*64 == NPAIR
            int d = pair % 19, b = pair / 19;
            float a = expf(tanhf(apre[tp1 * NPAIR + pair] + Fab[d]));
            int idx = b * G_SZ + d * 128 + k;
            float hvv = __bfloat162float(hcur[hidx(b, d * 128 + k)]);
            if (t == 1) gacc[idx] = a * hvv; else gacc[idx] += a * hvv;
            if (k == 0) {
                if (t == 1) asum[pair] = a; else asum[pair] += a;
                apre[tp1 * NPAIR + pair] = 0.0f;
            }
        }
    }

    // ---- j candidate GEMM: K=128 (this panel's h slice) ----
    f32x16 aj = (f32x16)0.0f;
    const bf16x8* pAj = (const bf16x8*)hcur + ((size_t)(mb * 2 + mi) * HFRAGS + nb * 8) * 64 + lane;
    const bf16x8* pBj = (const bf16x8*)Wjt2 + ((size_t)(nb * 4 + s) * 8) * 64 + lane;
#pragma unroll
    for (int k16 = 0; k16 < 8; ++k16)
        aj = __builtin_amdgcn_mfma_f32_32x32x16_bf16(pAj[k16 * 64], pBj[k16 * 64], aj, 0, 0, 0);

    // ---- epilogue: gates, cell update, alpha partial dot, h frag writeback ----
    const int colg = nb * 128 + s * 32 + (lane & 31);
    const int kw = colg & 127;
    const float wib = Wib[colg], wfb = Wfb[colg], wob = Wob[colg];
    const float uj = Uj[nb * 128 + kw], bjv = bj[nb * 128 + kw], fav = Fa[nb * 128 + kw];
    const int xcol = fmap(nb);
    const int rbase = mb * 64 + mi * 32;

#pragma unroll
    for (int q = 0; q < 16; ++q) {
        int r = (q & 3) + 8 * (q >> 2) + 4 * (lane >> 5);   // C/D row mapping (32x32)
        int b = rbase + r;
        float iv = sigmoidf_(acc0[q] + wib);
        float fv = sigmoidf_(acc1[q] + wfb);
        float ov = sigmoidf_(acc2[q] + wob);
        float xv = x[(b * T_SZ + t) * IN_DIMX + xcol];
        float jv = tanhf(aj[q] + xv * uj + bjv);
        float cold = (t > 0) ? cbuf[(size_t)b * G_SZ + colg] : 0.0f;
        float cv = cold * fv + iv * jv;
        cbuf[(size_t)b * G_SZ + colg] = cv;
        float hv = ov * tanhf(cv);
        strans[w][r * 32 + (lane & 31)] = __float2bfloat16(hv);
        float psum = hv * fav;
#pragma unroll
        for (int m2 = 1; m2 < 32; m2 <<= 1) psum += __shfl_xor(psum, m2, 64);
        if ((lane & 31) == 0) atomicAdd(&apre[(t & 1) * NPAIR + b * 19 + nb], psum);
    }
    // h writeback: per-wave LDS transpose (acc layout -> frag-linear), 2x 1KB stores
#pragma unroll
    for (int hh = 0; hh < 2; ++hh) {
        bf16x8 hv8 = *(const bf16x8*)&strans[w][(lane & 31) * 32 + hh * 16 + (lane >> 5) * 8];
        size_t frag = (size_t)(mb * 2 + mi) * HFRAGS + nb * 8 + s * 2 + hh;
        *((bf16x8*)hnext + frag * 64 + lane) = hv8;
    }
}

// ---------------- final: finish t=63 attention, betas/Phi head, limitation gates ----------------
__global__ __launch_bounds__(256) void final_kernel(
    const float* __restrict__ x,
    const __hip_bfloat16* __restrict__ h63,
    const float* __restrict__ apre, float* __restrict__ asum, float* __restrict__ gacc,
    const float* __restrict__ Fab,
    const float* __restrict__ Fbw, const float* __restrict__ Fbb,
    const float* __restrict__ Pw,  const float* __restrict__ Pb,
    const float* __restrict__ faw, const float* __restrict__ fab,
    const float* __restrict__ hsw, const float* __restrict__ hsb,
    float* __restrict__ out)
{
    const int b = blockIdx.x, tid = threadIdx.x;
    for (int e = tid; e < G_SZ; e += 256) {
        int d = e >> 7;
        float a = expf(tanhf(apre[NPAIR + b * 19 + d] + Fab[d]));
        gacc[b * G_SZ + e] += a * __bfloat162float(h63[hidx(b, e)]);
    }
    if (tid < 19) asum[b * 19 + tid] += expf(tanhf(apre[NPAIR + b * 19 + tid] + Fab[tid]));
    __syncthreads();

    const int wv = tid >> 6, lane = tid & 63;
    __shared__ float snum[4], sden[4];
    float num = 0.0f, den = 0.0f;
    for (int d = wv; d < 19; d += 4) {
        float asv = asum[b * 19 + d];
        float mua = 0.0f, bea = 0.0f;
#pragma unroll
        for (int j2 = 0; j2 < 4; ++j2) {
            int e = lane + j2 * 64;
            float hg = (e < 128) ? (gacc[b * G_SZ + d * 128 + e] / asv)
                                 : __bfloat162float(h63[hidx(b, d * 128 + (e - 128))]);
            mua += hg * Pw[e];
            bea += hg * Fbw[e];
        }
        for (int m = 1; m < 64; m <<= 1) { mua += __shfl_xor(mua, m, 64); bea += __shfl_xor(bea, m, 64); }
        if (lane == 0) {
            float mu = mua + Pb[0];
            float be = expf(tanhf(bea + Fbb[0]));
            num += be * mu; den += be;
        }
    }
    if (lane == 0) { snum[wv] = num; sden[wv] = den; }
    __syncthreads();
    if (tid == 0) {
        float n = 0.0f, dd = 0.0f;
        for (int w2 = 0; w2 < 4; ++w2) { n += snum[w2]; dd += sden[w2]; }
        float fFF = sigmoidf_(n / dd);
        float xn = x[(b * T_SZ + 63) * IN_DIMX + 0];
        float xp = x[(b * T_SZ + 63) * IN_DIMX + 16];
        float fn = sigmoidf_(xn * faw[0] + fab[0]);
        float fp = sigmoidf_(xp * hsw[0] + hsb[0]);
        out[b] = fFF * fn * fp;
    }
}

extern "C" void kernel_launch(void* const* d_in, const int* in_sizes, int n_in,
                              void* d_out, int out_size, void* d_ws, size_t ws_size,
                              hipStream_t stream) {
    const float* x   = (const float*)d_in[0];
    const float* Uj  = (const float*)d_in[1];
    const float* Wj  = (const float*)d_in[2];
    const float* bj  = (const float*)d_in[3];
    const float* Wi  = (const float*)d_in[4];
    const float* Wib = (const float*)d_in[5];
    const float* Wf  = (const float*)d_in[6];
    const float* Wfb = (const float*)d_in[7];
    const float* Wo  = (const float*)d_in[8];
    const float* Wob = (const float*)d_in[9];
    const float* Fa  = (const float*)d_in[10];
    const float* Fab = (const float*)d_in[11];
    const float* Fbw = (const float*)d_in[12];
    const float* Fbb = (const float*)d_in[13];
    const float* Pw  = (const float*)d_in[14];
    const float* Pb  = (const float*)d_in[15];
    const float* faw = (const float*)d_in[16];
    const float* fab = (const float*)d_in[17];
    const float* hsw = (const float*)d_in[18];
    const float* hsb = (const float*)d_in[19];

    char* ws = (char*)d_ws;
    size_t off = 0;
    auto alloc = [&](size_t bytes) { void* p = ws + off; off += (bytes + 255) & ~(size_t)255; return p; };

    __hip_bfloat16* Wt2  = (__hip_bfloat16*)alloc((size_t)3 * 19 * 4 * NK16 * 512 * 2);
    __hip_bfloat16* Wjt2 = (__hip_bfloat16*)alloc((size_t)19 * 4 * 8 * 512 * 2);
    __hip_bfloat16* xfr  = (__hip_bfloat16*)alloc((size_t)64 * 8 * 2 * 2 * 512 * 2);
    __hip_bfloat16* hfr  = (__hip_bfloat16*)alloc((size_t)2 * 8 * 2 * HFRAGS * 512 * 2);
    float* cbuf  = (float*)alloc((size_t)B_SZ * G_SZ * 4);
    float* apre  = (float*)alloc((size_t)2 * NPAIR * 4);
    float* asumb = (float*)alloc((size_t)NPAIR * 4);
    float* gacc  = (float*)alloc((size_t)B_SZ * G_SZ * 4);

    const size_t PREP_TOTAL = (size_t)3 * 19 * 4 * NK16 * 512 + 19 * 4 * 8 * 512
                            + (size_t)64 * 8 * 2 * 2 * 512 + (size_t)8 * 2 * HFRAGS * 512 + 2 * NPAIR;
    prep_kernel<<<(int)((PREP_TOTAL + 255) / 256), 256, 0, stream>>>(
        x, Wi, Wf, Wo, Wj, Wt2, Wjt2, xfr, hfr, apre);

    const size_t HB = (size_t)8 * 2 * HFRAGS * 512;
    for (int t = 0; t < T_SZ; ++t) {
        step_kernel<<<152, 512, 0, stream>>>(t, Wt2, Wjt2, xfr,
            hfr + (t & 1) * HB, hfr + ((t + 1) & 1) * HB,
            cbuf, apre, asumb, gacc,
            x, Uj, bj, Wib, Wfb, Wob, Fa, Fab);
    }
    final_kernel<<<B_SZ, 256, 0, stream>>>(x, hfr /* ring[0] = h(64) */, apre, asumb, gacc,
        Fab, Fbw, Fbb, Pw, Pb, faw, fab, hsw, hsb, (float*)d_out);
}

// Round 4
// 5019.386 us; speedup vs baseline: 1.6413x; 1.0183x over previous
//
#include <hip/hip_runtime.h>
#include <hip/hip_bf16.h>

// Fire_model_hybrid: IMV-LSTM scan (T=64) + temporal attention + head.
// v4: persistent kernel — all 64 steps in one launch with a hand-rolled grid
// barrier. Weights L2-resident (same block re-reads its panel each step),
// c and gacc in registers, attention fused per-step (no apre/atomics).
// Frag-linear layouts and MFMA wiring carried over from v3 (verified).

#define B_SZ 512
#define T_SZ 64
#define IN_DIMX 21
#define D_F 19
#define G_SZ 2432        // D_F * 128
#define NPAIR 9728       // B_SZ * D_F
#define NK16 154         // 2464/16 : 152 h-frags + 2 x-frags
#define HFRAGS 152
#define NBLK 152

typedef __attribute__((ext_vector_type(8))) short bf16x8;
typedef __attribute__((ext_vector_type(16))) float f32x16;

__device__ __forceinline__ float sigmoidf_(float v) { return 1.0f / (1.0f + expf(-v)); }
__device__ __forceinline__ int fmap(int j) { return j < 16 ? j : j + 2; }

// h frag-layout: [mb 8][mi 2][k16 152][lane 64][e 8]
__device__ __forceinline__ size_t hidx(int b, int gg) {
    int mb2 = b >> 6, r = b & 63, mi = r >> 5, bl = r & 31;
    int k16 = gg >> 4, half = (gg >> 3) & 1, e = gg & 7;
    return ((((size_t)(mb2 * 2 + mi) * HFRAGS + k16) * 64) + bl + 32 * half) * 8 + e;
}

// ---------------- preprocess: frag-linear packing + zero-init (incl. barrier state) ----------------
__global__ __launch_bounds__(256) void prep_kernel(
    const float* __restrict__ x,
    const float* __restrict__ Wi, const float* __restrict__ Wf, const float* __restrict__ Wo,
    const float* __restrict__ Wj,
    __hip_bfloat16* __restrict__ Wt2,   // [3][19][4][154][512]
    __hip_bfloat16* __restrict__ Wjt2,  // [19][4][8][512]
    __hip_bfloat16* __restrict__ xfr,   // [64][8][2][2][512]
    __hip_bfloat16* __restrict__ hfr0,  // [8][2][152][512]
    int* __restrict__ sync)             // [64] barrier state (cnt, gen, ...)
{
    int i = blockIdx.x * 256 + threadIdx.x;
    const int NWT = 3 * 19 * 4 * NK16 * 512;
    if (i < NWT) {
        int e = i & 7, lane = (i >> 3) & 63, fi = i >> 9;
        int k16 = fi % NK16, ff = fi / NK16;
        int s = ff & 3, ff2 = ff >> 2;
        int d = ff2 % 19, gate = ff2 / 19;
        int gcol = d * 128 + s * 32 + (lane & 31);
        int k = k16 * 16 + (lane >> 5) * 8 + e;
        const float* W = gate == 0 ? Wi : (gate == 1 ? Wf : Wo);
        float v = 0.0f;
        if (k < 2432)      v = W[gcol * 2451 + 19 + k];
        else if (k < 2451) v = W[gcol * 2451 + (k - 2432)];
        Wt2[i] = __float2bfloat16(v);
        return;
    }
    i -= NWT;
    if (i < 19 * 4 * 8 * 512) {
        int e = i & 7, lane = (i >> 3) & 63, fi = i >> 9;
        int k16 = fi & 7, ff = fi >> 3;
        int s = ff & 3, d = ff >> 2;
        int col = s * 32 + (lane & 31);
        int kin = k16 * 16 + (lane >> 5) * 8 + e;
        Wjt2[i] = __float2bfloat16(Wj[d * 16384 + kin * 128 + col]);
        return;
    }
    i -= 19 * 4 * 8 * 512;
    if (i < 64 * 8 * 2 * 2 * 512) {
        int e = i & 7, lane = (i >> 3) & 63, fi = i >> 9;
        int k16 = fi & 1, ff = fi >> 1;
        int mi = ff & 1, ff2 = ff >> 1;
        int mb = ff2 & 7, tt = ff2 >> 3;
        int b = mb * 64 + mi * 32 + (lane & 31);
        int kloc = k16 * 16 + (lane >> 5) * 8 + e;
        float v = 0.0f;
        if (kloc < 19) v = x[(b * T_SZ + tt) * IN_DIMX + fmap(kloc)];
        xfr[i] = __float2bfloat16(v);
        return;
    }
    i -= 64 * 8 * 2 * 2 * 512;
    if (i < 8 * 2 * HFRAGS * 512) { hfr0[i] = __float2bfloat16(0.0f); return; }
    i -= 8 * 2 * HFRAGS * 512;
    if (i < 64) sync[i] = 0;
}

#define SBAR __builtin_amdgcn_sched_barrier(0)

#define LOADSET(aa0, aa1, b00, b01, b10, b11, b20, b21, kk) do { \
    int f_ = 2 * (kk); \
    if ((kk) == 76) { aa0 = pAx[0]; aa1 = pAx[64]; } \
    else { aa0 = pA[(size_t)f_ * 64]; aa1 = pA[(size_t)f_ * 64 + 64]; } \
    b00 = pB0[(size_t)f_ * 64]; b01 = pB0[(size_t)f_ * 64 + 64]; \
    b10 = pB1[(size_t)f_ * 64]; b11 = pB1[(size_t)f_ * 64 + 64]; \
    b20 = pB2[(size_t)f_ * 64]; b21 = pB2[(size_t)f_ * 64 + 64]; } while (0)

#define MFMASET(aa0, aa1, b00, b01, b10, b11, b20, b21) do { \
    acc0 = __builtin_amdgcn_mfma_f32_32x32x16_bf16(aa0, b00, acc0, 0, 0, 0); \
    acc1 = __builtin_amdgcn_mfma_f32_32x32x16_bf16(aa0, b10, acc1, 0, 0, 0); \
    acc2 = __builtin_amdgcn_mfma_f32_32x32x16_bf16(aa0, b20, acc2, 0, 0, 0); \
    acc0 = __builtin_amdgcn_mfma_f32_32x32x16_bf16(aa1, b01, acc0, 0, 0, 0); \
    acc1 = __builtin_amdgcn_mfma_f32_32x32x16_bf16(aa1, b11, acc1, 0, 0, 0); \
    acc2 = __builtin_amdgcn_mfma_f32_32x32x16_bf16(aa1, b21, acc2, 0, 0, 0); } while (0)

// ---------------- persistent scan kernel ----------------
__global__ __launch_bounds__(512, 2) void step_persist(
    const __hip_bfloat16* __restrict__ Wt2,
    const __hip_bfloat16* __restrict__ Wjt2,
    const __hip_bfloat16* __restrict__ xfr,
    __hip_bfloat16* __restrict__ hfr,   // [2][8][2][152][512]
    float* __restrict__ gaccG,          // [B][G_SZ]
    float* __restrict__ asumG,          // [NPAIR]
    int* __restrict__ sync,
    const float* __restrict__ x,
    const float* __restrict__ Uj, const float* __restrict__ bj,
    const float* __restrict__ Wib, const float* __restrict__ Wfb, const float* __restrict__ Wob,
    const float* __restrict__ Fa, const float* __restrict__ Fab)
{
    __shared__ __align__(16) __hip_bfloat16 strans[8][1024];   // 16 KB per-wave transpose
    __shared__ float a_lds[64];
    const int tid = threadIdx.x;
    const int bid = blockIdx.x;

    // XCD-grouped (nb -> XCD) mapping for the first 16 panels; last 3 spread.
    int nb, mb;
    if (bid < 128) { int xc = bid & 7, j = bid >> 3; nb = (j >> 3) * 8 + xc; mb = j & 7; }
    else           { int r2 = bid - 128; nb = 16 + (r2 >> 3); mb = r2 & 7; }

    const int w = tid >> 6, lane = tid & 63;
    const int mi = w >> 2, s = w & 3;
    const int rl = lane & 15; (void)rl;

    // per-lane invariants
    const int colg = nb * 128 + s * 32 + (lane & 31);
    const int kw = colg & 127;
    const float wib = Wib[colg], wfb = Wfb[colg], wob = Wob[colg];
    const float uj = Uj[nb * 128 + kw], bjv = bj[nb * 128 + kw], fav = Fa[nb * 128 + kw];
    const float fab_s = Fab[nb];
    const int xcol = fmap(nb);
    const int rbase = mb * 64 + mi * 32;
    const size_t HB = (size_t)8 * 2 * HFRAGS * 512;

    float cc[16], gaccr[16];
#pragma unroll
    for (int q = 0; q < 16; ++q) { cc[q] = 0.0f; gaccr[q] = 0.0f; }
    float asum_r = 0.0f;

    if (w == 0) a_lds[lane] = 0.0f;
    __syncthreads();

    const bf16x8* pB0 = (const bf16x8*)Wt2 + ((size_t)(0 * 76 + nb * 4 + s) * NK16) * 64 + lane;
    const bf16x8* pB1 = (const bf16x8*)Wt2 + ((size_t)(1 * 76 + nb * 4 + s) * NK16) * 64 + lane;
    const bf16x8* pB2 = (const bf16x8*)Wt2 + ((size_t)(2 * 76 + nb * 4 + s) * NK16) * 64 + lane;
    const bf16x8* pBj = (const bf16x8*)Wjt2 + ((size_t)(nb * 4 + s) * 8) * 64 + lane;

#pragma unroll 1
    for (int t = 0; t < T_SZ; ++t) {
        const __hip_bfloat16* hcur = hfr + (t & 1) * HB;
        __hip_bfloat16* hnext = hfr + ((t + 1) & 1) * HB;

        const bf16x8* pA  = (const bf16x8*)hcur + ((size_t)(mb * 2 + mi) * HFRAGS) * 64 + lane;
        const bf16x8* pAx = (const bf16x8*)xfr + ((size_t)((t * 8 + mb) * 2 + mi) * 2) * 64 + lane;

        f32x16 acc0 = (f32x16)0.0f, acc1 = (f32x16)0.0f, acc2 = (f32x16)0.0f;
        bf16x8 aE0, aE1, bE00, bE01, bE10, bE11, bE20, bE21;
        bf16x8 aO0, aO1, bO00, bO01, bO10, bO11, bO20, bO21;

        LOADSET(aE0, aE1, bE00, bE01, bE10, bE11, bE20, bE21, 0);
        for (int kk2 = 0; kk2 < 39; ++kk2) {
            if (kk2 < 38) { SBAR; LOADSET(aO0, aO1, bO00, bO01, bO10, bO11, bO20, bO21, 2 * kk2 + 1); SBAR; }
            MFMASET(aE0, aE1, bE00, bE01, bE10, bE11, bE20, bE21);
            if (kk2 < 38) {
                SBAR; LOADSET(aE0, aE1, bE00, bE01, bE10, bE11, bE20, bE21, 2 * kk2 + 2); SBAR;
                MFMASET(aO0, aO1, bO00, bO01, bO10, bO11, bO20, bO21);
            }
        }

        // ---- j candidate GEMM: K=128 (this panel's h slice), direct loads (L2-hot) ----
        f32x16 aj = (f32x16)0.0f;
        const bf16x8* pAj = (const bf16x8*)hcur + ((size_t)(mb * 2 + mi) * HFRAGS + nb * 8) * 64 + lane;
#pragma unroll
        for (int k16 = 0; k16 < 8; ++k16)
            aj = __builtin_amdgcn_mfma_f32_32x32x16_bf16(pAj[k16 * 64], pBj[k16 * 64], aj, 0, 0, 0);

        // ---- epilogue: gates, cell update (c in regs), h write, alpha partial dot ----
#pragma unroll
        for (int q = 0; q < 16; ++q) {
            int r = (q & 3) + 8 * (q >> 2) + 4 * (lane >> 5);   // C/D row mapping (32x32)
            int b = rbase + r;
            float iv = sigmoidf_(acc0[q] + wib);
            float fv = sigmoidf_(acc1[q] + wfb);
            float ov = sigmoidf_(acc2[q] + wob);
            float xv = x[(b * T_SZ + t) * IN_DIMX + xcol];
            float jv = tanhf(aj[q] + xv * uj + bjv);
            float cv = cc[q] * fv + iv * jv;
            cc[q] = cv;
            float hv = ov * tanhf(cv);
            strans[w][r * 32 + (lane & 31)] = __float2bfloat16(hv);
            float psum = hv * fav;
#pragma unroll
            for (int m2 = 1; m2 < 32; m2 <<= 1) psum += __shfl_xor(psum, m2, 64);
            if ((lane & 31) == 0) atomicAdd(&a_lds[mi * 32 + r], psum);
        }
        // h writeback: per-wave LDS transpose (acc layout -> frag-linear)
#pragma unroll
        for (int hh = 0; hh < 2; ++hh) {
            bf16x8 hv8 = *(const bf16x8*)&strans[w][(lane & 31) * 32 + hh * 16 + (lane >> 5) * 8];
            size_t frag = (size_t)(mb * 2 + mi) * HFRAGS + nb * 8 + s * 2 + hh;
            *((bf16x8*)hnext + frag * 64 + lane) = hv8;
        }

        // ---- attention: a = exp(tanh(dot + Fab)); gacc += a*h; asum += a ----
        __syncthreads();
        if (w == 0) {
            float av = expf(tanhf(a_lds[lane] + fab_s));
            a_lds[lane] = av;
            asum_r += av;
        }
        __syncthreads();
#pragma unroll
        for (int q = 0; q < 16; ++q) {
            int r = (q & 3) + 8 * (q >> 2) + 4 * (lane >> 5);
            gaccr[q] += a_lds[mi * 32 + r] * __bfloat162float(strans[w][r * 32 + (lane & 31)]);
        }
        __syncthreads();
        if (w == 0) a_lds[lane] = 0.0f;

        // ---- grid barrier (release/acquire via device-scope atomics + fences) ----
        __syncthreads();                 // drains this block's vmem (h stores)
        if (tid == 0) {
            __threadfence();             // release: L2 writeback (agent scope)
            int v = atomicAdd(&sync[0], 1);
            if (v == NBLK * (t + 1) - 1) {
                atomicExch(&sync[1], t + 1);
            } else {
                while (atomicAdd(&sync[1], 0) < t + 1) __builtin_amdgcn_s_sleep(8);
            }
            __threadfence();             // acquire: invalidate stale L1/L2 lines
        }
        __syncthreads();
    }

    // ---- write attention accumulators for the final head kernel ----
#pragma unroll
    for (int q = 0; q < 16; ++q) {
        int r = (q & 3) + 8 * (q >> 2) + 4 * (lane >> 5);
        gaccG[(size_t)(rbase + r) * G_SZ + colg] = gaccr[q];
    }
    if (w == 0) asumG[(mb * 64 + lane) * 19 + nb] = asum_r;
}

// ---------------- final: betas/Phi head, limitation gates ----------------
__global__ __launch_bounds__(256) void final_kernel(
    const float* __restrict__ x,
    const __hip_bfloat16* __restrict__ h63,   // hfr[0] = h(64)
    const float* __restrict__ asum, const float* __restrict__ gacc,
    const float* __restrict__ Fbw, const float* __restrict__ Fbb,
    const float* __restrict__ Pw,  const float* __restrict__ Pb,
    const float* __restrict__ faw, const float* __restrict__ fab,
    const float* __restrict__ hsw, const float* __restrict__ hsb,
    float* __restrict__ out)
{
    const int b = blockIdx.x, tid = threadIdx.x;
    const int wv = tid >> 6, lane = tid & 63;
    __shared__ float snum[4], sden[4];
    float num = 0.0f, den = 0.0f;
    for (int d = wv; d < 19; d += 4) {
        float asv = asum[b * 19 + d];
        float mua = 0.0f, bea = 0.0f;
#pragma unroll
        for (int j2 = 0; j2 < 4; ++j2) {
            int e = lane + j2 * 64;
            float hg = (e < 128) ? (gacc[b * G_SZ + d * 128 + e] / asv)
                                 : __bfloat162float(h63[hidx(b, d * 128 + (e - 128))]);
            mua += hg * Pw[e];
            bea += hg * Fbw[e];
        }
        for (int m = 1; m < 64; m <<= 1) { mua += __shfl_xor(mua, m, 64); bea += __shfl_xor(bea, m, 64); }
        if (lane == 0) {
            float mu = mua + Pb[0];
            float be = expf(tanhf(bea + Fbb[0]));
            num += be * mu; den += be;
        }
    }
    if (lane == 0) { snum[wv] = num; sden[wv] = den; }
    __syncthreads();
    if (tid == 0) {
        float n = 0.0f, dd = 0.0f;
        for (int w2 = 0; w2 < 4; ++w2) { n += snum[w2]; dd += sden[w2]; }
        float fFF = sigmoidf_(n / dd);
        float xn = x[(b * T_SZ + 63) * IN_DIMX + 0];
        float xp = x[(b * T_SZ + 63) * IN_DIMX + 16];
        float fn = sigmoidf_(xn * faw[0] + fab[0]);
        float fp = sigmoidf_(xp * hsw[0] + hsb[0]);
        out[b] = fFF * fn * fp;
    }
}

extern "C" void kernel_launch(void* const* d_in, const int* in_sizes, int n_in,
                              void* d_out, int out_size, void* d_ws, size_t ws_size,
                              hipStream_t stream) {
    const float* x   = (const float*)d_in[0];
    const float* Uj  = (const float*)d_in[1];
    const float* Wj  = (const float*)d_in[2];
    const float* bj  = (const float*)d_in[3];
    const float* Wi  = (const float*)d_in[4];
    const float* Wib = (const float*)d_in[5];
    const float* Wf  = (const float*)d_in[6];
    const float* Wfb = (const float*)d_in[7];
    const float* Wo  = (const float*)d_in[8];
    const float* Wob = (const float*)d_in[9];
    const float* Fa  = (const float*)d_in[10];
    const float* Fab = (const float*)d_in[11];
    const float* Fbw = (const float*)d_in[12];
    const float* Fbb = (const float*)d_in[13];
    const float* Pw  = (const float*)d_in[14];
    const float* Pb  = (const float*)d_in[15];
    const float* faw = (const float*)d_in[16];
    const float* fab = (const float*)d_in[17];
    const float* hsw = (const float*)d_in[18];
    const float* hsb = (const float*)d_in[19];

    char* ws = (char*)d_ws;
    size_t off = 0;
    auto alloc = [&](size_t bytes) { void* p = ws + off; off += (bytes + 255) & ~(size_t)255; return p; };

    __hip_bfloat16* Wt2  = (__hip_bfloat16*)alloc((size_t)3 * 19 * 4 * NK16 * 512 * 2);
    __hip_bfloat16* Wjt2 = (__hip_bfloat16*)alloc((size_t)19 * 4 * 8 * 512 * 2);
    __hip_bfloat16* xfr  = (__hip_bfloat16*)alloc((size_t)64 * 8 * 2 * 2 * 512 * 2);
    __hip_bfloat16* hfr  = (__hip_bfloat16*)alloc((size_t)2 * 8 * 2 * HFRAGS * 512 * 2);
    float* gacc  = (float*)alloc((size_t)B_SZ * G_SZ * 4);
    float* asumb = (float*)alloc((size_t)NPAIR * 4);
    int*   syncb = (int*)alloc(64 * 4);

    const size_t PREP_TOTAL = (size_t)3 * 19 * 4 * NK16 * 512 + 19 * 4 * 8 * 512
                            + (size_t)64 * 8 * 2 * 2 * 512 + (size_t)8 * 2 * HFRAGS * 512 + 64;
    prep_kernel<<<(int)((PREP_TOTAL + 255) / 256), 256, 0, stream>>>(
        x, Wi, Wf, Wo, Wj, Wt2, Wjt2, xfr, hfr, syncb);

    step_persist<<<NBLK, 512, 0, stream>>>(Wt2, Wjt2, xfr, hfr, gacc, asumb, syncb,
        x, Uj, bj, Wib, Wfb, Wob, Fa, Fab);

    final_kernel<<<B_SZ, 256, 0, stream>>>(x, hfr /* parity 0 = h(64) */, asumb, gacc,
        Fbw, Fbb, Pw, Pb, faw, fab, hsw, hsb, (float*)d_out);
}